// Round 1
// baseline (1137.979 us; speedup 1.0000x reference)
//
#include <hip/hip_runtime.h>
#include <hip/hip_bf16.h>
#include <math.h>

#define N_NODES 50000
#define N_EDGES 800000
#define HID 64

// ---------------------------------------------------------------------------
// Kernel 1: initial LayerNorm over 32 features. One 32-lane half-wave per node.
// block 256 = 4 waves = 8 nodes; grid 6250 (exact).
__global__ void ln0_kernel(const float* __restrict__ x,
                           const float* __restrict__ g,
                           const float* __restrict__ b,
                           float* __restrict__ h0) {
    int lane = threadIdx.x & 63;
    int n = blockIdx.x * 8 + (threadIdx.x >> 6) * 2 + (lane >> 5);
    int c = lane & 31;
    float v = x[n * 32 + c];
    float s = v;
    #pragma unroll
    for (int off = 1; off < 32; off <<= 1) s += __shfl_xor(s, off);
    float mu = s * (1.0f / 32.0f);
    float d = v - mu;
    float vs = d * d;
    #pragma unroll
    for (int off = 1; off < 32; off <<= 1) vs += __shfl_xor(vs, off);
    float var = vs * (1.0f / 32.0f);
    float y = d * rsqrtf(var + 1e-5f) * g[c] + b[c];
    h0[n * 32 + c] = y;
}

// ---------------------------------------------------------------------------
// CSR build: degree count, exclusive scan, scatter fill.
__global__ void deg_kernel(const int* __restrict__ dst, int* __restrict__ deg) {
    int e = blockIdx.x * blockDim.x + threadIdx.x;
    if (e >= N_EDGES) return;
    atomicAdd(&deg[dst[e]], 1);
}

// single block of 64 threads; wave-level chunked exclusive scan
__global__ void scan_kernel(const int* __restrict__ deg,
                            int* __restrict__ row_ptr,
                            int* __restrict__ cursor) {
    int lane = threadIdx.x;
    int carry = 0;
    for (int base = 0; base < N_NODES; base += 64) {
        int i = base + lane;
        int v = (i < N_NODES) ? deg[i] : 0;
        int incl = v;
        #pragma unroll
        for (int off = 1; off < 64; off <<= 1) {
            int t = __shfl_up(incl, off);
            if (lane >= off) incl += t;
        }
        int excl = carry + incl - v;
        if (i < N_NODES) { row_ptr[i] = excl; cursor[i] = excl; }
        carry += __shfl(incl, 63);
    }
    if (lane == 0) row_ptr[N_NODES] = carry;
}

__global__ void fill_kernel(const int* __restrict__ src,
                            const int* __restrict__ dst,
                            int* __restrict__ cursor,
                            int* __restrict__ colb) {
    int e = blockIdx.x * blockDim.x + threadIdx.x;
    if (e >= N_EDGES) return;
    int d = dst[e];
    int pos = atomicAdd(&cursor[d], 1);
    colb[pos] = src[e];
}

// ---------------------------------------------------------------------------
// Kernel: per-node Q/K/V/Skip projections. block 256, one block per node.
// wave w computes {Q,K,V,S}[w]'s 64 output columns.
__global__ void qkvs_kernel(const float* __restrict__ h, int d,
                            const float* __restrict__ Wq, const float* __restrict__ bq,
                            const float* __restrict__ Wk, const float* __restrict__ bk,
                            const float* __restrict__ Wv, const float* __restrict__ bv,
                            const float* __restrict__ Ws,
                            float* __restrict__ Q, float* __restrict__ K,
                            float* __restrict__ V, float* __restrict__ S) {
    __shared__ float sh[HID];
    int n = blockIdx.x;
    int t = threadIdx.x;
    if (t < d) sh[t] = h[n * d + t];
    __syncthreads();
    int which = t >> 6;
    int j = t & 63;
    const float* W; const float* bias; float* out;
    if (which == 0)      { W = Wq; bias = bq; out = Q; }
    else if (which == 1) { W = Wk; bias = bk; out = K; }
    else if (which == 2) { W = Wv; bias = bv; out = V; }
    else                 { W = Ws; bias = nullptr; out = S; }
    float acc = bias ? bias[j] : 0.0f;
    #pragma unroll 8
    for (int i = 0; i < d; i++) acc = fmaf(sh[i], W[i * 64 + j], acc);
    out[n * 64 + j] = acc;
}

// ---------------------------------------------------------------------------
// Kernel: per-node attention aggregation (online softmax) + skip + LayerNorm
// + optional residual + optional ReLU. One wave per node; lane = head*C + c.
// block 256 = 4 waves = 4 nodes; grid 12500 (exact).
template <int HEADS, bool RES, bool RELU>
__global__ void agg_kernel(const float* __restrict__ Q, const float* __restrict__ K,
                           const float* __restrict__ V, const float* __restrict__ S,
                           const int* __restrict__ row_ptr, const int* __restrict__ colb,
                           const float* __restrict__ g, const float* __restrict__ b,
                           const float* __restrict__ h_in, float* __restrict__ h_out) {
    constexpr int C = HID / HEADS;
    int lane = threadIdx.x & 63;
    int n = blockIdx.x * 4 + (threadIdx.x >> 6);

    float q = Q[n * 64 + lane];
    int beg = row_ptr[n], end = row_ptr[n + 1];

    const float scale = rsqrtf((float)C);
    float m = -1e30f, ssum = 0.0f, acc = 0.0f;

    for (int base = beg; base < end; base += 64) {
        int cnt = min(64, end - base);
        int src_l = (base + lane < end) ? colb[base + lane] : 0;
        for (int j = 0; j < cnt; j++) {
            int src = __shfl(src_l, j);
            float k = K[src * 64 + lane];
            float v = V[src * 64 + lane];
            float t = q * k;
            #pragma unroll
            for (int off = 1; off < C; off <<= 1) t += __shfl_xor(t, off);
            float score = t * scale;
            float nm = fmaxf(m, score);
            float escale = __expf(m - nm);
            float p = __expf(score - nm);
            acc = acc * escale + p * v;
            ssum = ssum * escale + p;
            m = nm;
        }
    }

    float outf = acc / (ssum + 1e-16f) + S[n * 64 + lane];

    // LayerNorm across the 64 lanes (= 64 features)
    float s = outf;
    #pragma unroll
    for (int off = 1; off < 64; off <<= 1) s += __shfl_xor(s, off);
    float mu = s * (1.0f / 64.0f);
    float d = outf - mu;
    float vs = d * d;
    #pragma unroll
    for (int off = 1; off < 64; off <<= 1) vs += __shfl_xor(vs, off);
    float var = vs * (1.0f / 64.0f);
    float y = d * rsqrtf(var + 1e-5f) * g[lane] + b[lane];
    if (RES)  y += 0.1f * h_in[n * 64 + lane];
    if (RELU) y = fmaxf(y, 0.0f);
    h_out[n * 64 + lane] = y;
}

// ---------------------------------------------------------------------------
// Kernel: final two MLP heads. One wave per node; lanes 0-31 -> rtt path,
// lanes 32-63 -> retrans path. block 256 = 4 nodes; grid 12500 (exact).
__global__ void head_kernel(const float* __restrict__ h,
                            const float* __restrict__ Wr1, const float* __restrict__ br1,
                            const float* __restrict__ Wr2, const float* __restrict__ br2,
                            const float* __restrict__ Wt1, const float* __restrict__ bt1,
                            const float* __restrict__ Wt2, const float* __restrict__ bt2,
                            float* __restrict__ out) {
    __shared__ float sh[4][HID];
    int wave = threadIdx.x >> 6;
    int lane = threadIdx.x & 63;
    int n = blockIdx.x * 4 + wave;
    sh[wave][lane] = h[n * 64 + lane];
    __syncthreads();
    int half = lane >> 5;
    int j = lane & 31;
    const float* W1 = half ? Wt1 : Wr1;
    const float* b1 = half ? bt1 : br1;
    const float* W2 = half ? Wt2 : Wr2;
    const float* b2 = half ? bt2 : br2;
    float a = b1[j];
    #pragma unroll 8
    for (int i = 0; i < 64; i++) a = fmaf(sh[wave][i], W1[i * 32 + j], a);
    a = fmaxf(a, 0.0f);
    float r = a * W2[j];
    #pragma unroll
    for (int off = 1; off < 32; off <<= 1) r += __shfl_xor(r, off);
    if (j == 0) out[n * 2 + half] = r + b2[0];
}

// ---------------------------------------------------------------------------
extern "C" void kernel_launch(void* const* d_in, const int* in_sizes, int n_in,
                              void* d_out, int out_size, void* d_ws, size_t ws_size,
                              hipStream_t stream) {
    const float* x    = (const float*)d_in[0];
    const int*   ei   = (const int*)d_in[1];
    const int*   src  = ei;
    const int*   dst  = ei + N_EDGES;
    const float* ln0g = (const float*)d_in[2];
    const float* ln0b = (const float*)d_in[3];

    // per-layer params: Wq,bq,Wk,bk,Wv,bv,Ws,g,b  at base 4 + 9*l
    const float* P[27];
    for (int i = 0; i < 27; i++) P[i] = (const float*)d_in[4 + i];
    const float* Wr1 = (const float*)d_in[31];
    const float* br1 = (const float*)d_in[32];
    const float* Wr2 = (const float*)d_in[33];
    const float* br2 = (const float*)d_in[34];
    const float* Wt1 = (const float*)d_in[35];
    const float* bt1 = (const float*)d_in[36];
    const float* Wt2 = (const float*)d_in[37];
    const float* bt2 = (const float*)d_in[38];

    float* out = (float*)d_out;

    // workspace layout
    float* hbuf0 = (float*)d_ws;                 // N*64
    float* hbuf1 = hbuf0 + N_NODES * 64;         // N*64
    float* Qb    = hbuf1 + N_NODES * 64;
    float* Kb    = Qb + N_NODES * 64;
    float* Vb    = Kb + N_NODES * 64;
    float* Sb    = Vb + N_NODES * 64;
    int* row_ptr = (int*)(Sb + N_NODES * 64);    // N+1
    int* cursor  = row_ptr + (N_NODES + 1);      // N
    int* deg     = cursor + N_NODES;             // N
    int* colb    = deg + N_NODES;                // E

    // ---- graph structure (rebuilt every launch; ws is re-poisoned) ----
    hipMemsetAsync(deg, 0, N_NODES * sizeof(int), stream);
    ln0_kernel<<<6250, 256, 0, stream>>>(x, ln0g, ln0b, hbuf0);
    deg_kernel<<<(N_EDGES + 255) / 256, 256, 0, stream>>>(dst, deg);
    scan_kernel<<<1, 64, 0, stream>>>(deg, row_ptr, cursor);
    fill_kernel<<<(N_EDGES + 255) / 256, 256, 0, stream>>>(src, dst, cursor, colb);

    // ---- layer 0: 32 -> 64, heads=4, no residual, relu ----
    qkvs_kernel<<<N_NODES, 256, 0, stream>>>(hbuf0, 32,
        P[0], P[1], P[2], P[3], P[4], P[5], P[6], Qb, Kb, Vb, Sb);
    agg_kernel<4, false, true><<<12500, 256, 0, stream>>>(Qb, Kb, Vb, Sb,
        row_ptr, colb, P[7], P[8], nullptr, hbuf1);

    // ---- layer 1: 64 -> 64, heads=4, residual, relu ----
    qkvs_kernel<<<N_NODES, 256, 0, stream>>>(hbuf1, 64,
        P[9], P[10], P[11], P[12], P[13], P[14], P[15], Qb, Kb, Vb, Sb);
    agg_kernel<4, true, true><<<12500, 256, 0, stream>>>(Qb, Kb, Vb, Sb,
        row_ptr, colb, P[16], P[17], hbuf1, hbuf0);

    // ---- layer 2: 64 -> 64, heads=1, residual, no relu ----
    qkvs_kernel<<<N_NODES, 256, 0, stream>>>(hbuf0, 64,
        P[18], P[19], P[20], P[21], P[22], P[23], P[24], Qb, Kb, Vb, Sb);
    agg_kernel<1, true, false><<<12500, 256, 0, stream>>>(Qb, Kb, Vb, Sb,
        row_ptr, colb, P[25], P[26], hbuf0, hbuf1);

    // ---- MLP heads ----
    head_kernel<<<12500, 256, 0, stream>>>(hbuf1,
        Wr1, br1, Wr2, br2, Wt1, bt1, Wt2, bt2, out);
}

// Round 2
// 771.247 us; speedup vs baseline: 1.4755x; 1.4755x over previous
//
#include <hip/hip_runtime.h>
#include <hip/hip_bf16.h>
#include <math.h>

#define N_NODES 50000
#define N_EDGES 800000
#define HID 64
#define N_CHUNKS ((N_NODES + 255) / 256)   // 196

// ---------------------------------------------------------------------------
// Kernel 1: initial LayerNorm over 32 features. One 32-lane half-wave per node.
__global__ void ln0_kernel(const float* __restrict__ x,
                           const float* __restrict__ g,
                           const float* __restrict__ b,
                           float* __restrict__ h0) {
    int lane = threadIdx.x & 63;
    int n = blockIdx.x * 8 + (threadIdx.x >> 6) * 2 + (lane >> 5);
    int c = lane & 31;
    float v = x[n * 32 + c];
    float s = v;
    #pragma unroll
    for (int off = 1; off < 32; off <<= 1) s += __shfl_xor(s, off);
    float mu = s * (1.0f / 32.0f);
    float d = v - mu;
    float vs = d * d;
    #pragma unroll
    for (int off = 1; off < 32; off <<= 1) vs += __shfl_xor(vs, off);
    float var = vs * (1.0f / 32.0f);
    float y = d * rsqrtf(var + 1e-5f) * g[c] + b[c];
    h0[n * 32 + c] = y;
}

// ---------------------------------------------------------------------------
// CSR build: degree count, 3-phase hierarchical exclusive scan, scatter fill.
__global__ void deg_kernel(const int* __restrict__ dst, int* __restrict__ deg) {
    int e = blockIdx.x * blockDim.x + threadIdx.x;
    if (e >= N_EDGES) return;
    atomicAdd(&deg[dst[e]], 1);
}

// phase 1: per-256-chunk sums. grid N_CHUNKS, block 256.
__global__ void chunk_sum_kernel(const int* __restrict__ deg, int* __restrict__ csum) {
    int i = blockIdx.x * 256 + threadIdx.x;
    int v = (i < N_NODES) ? deg[i] : 0;
    #pragma unroll
    for (int off = 1; off < 64; off <<= 1) v += __shfl_xor(v, off);
    __shared__ int ws[4];
    if ((threadIdx.x & 63) == 0) ws[threadIdx.x >> 6] = v;
    __syncthreads();
    if (threadIdx.x == 0) csum[blockIdx.x] = ws[0] + ws[1] + ws[2] + ws[3];
}

// phase 2: single wave scans the 196 chunk sums (exclusive), writes total.
__global__ void scan_sums_kernel(const int* __restrict__ csum,
                                 int* __restrict__ coff,
                                 int* __restrict__ row_ptr) {
    int lane = threadIdx.x;
    int carry = 0;
    for (int base = 0; base < N_CHUNKS; base += 64) {
        int i = base + lane;
        int v = (i < N_CHUNKS) ? csum[i] : 0;
        int incl = v;
        #pragma unroll
        for (int off = 1; off < 64; off <<= 1) {
            int t = __shfl_up(incl, off);
            if (lane >= off) incl += t;
        }
        if (i < N_CHUNKS) coff[i] = carry + incl - v;
        carry += __shfl(incl, 63);
    }
    if (lane == 0) row_ptr[N_NODES] = carry;
}

// phase 3: intra-chunk exclusive scan + chunk offset. grid N_CHUNKS, block 256.
__global__ void scan_final_kernel(const int* __restrict__ deg,
                                  const int* __restrict__ coff,
                                  int* __restrict__ row_ptr,
                                  int* __restrict__ cursor) {
    int i = blockIdx.x * 256 + threadIdx.x;
    int lane = threadIdx.x & 63;
    int w = threadIdx.x >> 6;
    int v = (i < N_NODES) ? deg[i] : 0;
    int incl = v;
    #pragma unroll
    for (int off = 1; off < 64; off <<= 1) {
        int t = __shfl_up(incl, off);
        if (lane >= off) incl += t;
    }
    __shared__ int ws[4];
    if (lane == 63) ws[w] = incl;
    __syncthreads();
    int woff = 0;
    #pragma unroll
    for (int k = 0; k < 4; k++) if (k < w) woff += ws[k];
    int excl = coff[blockIdx.x] + woff + incl - v;
    if (i < N_NODES) { row_ptr[i] = excl; cursor[i] = excl; }
}

__global__ void fill_kernel(const int* __restrict__ src,
                            const int* __restrict__ dst,
                            int* __restrict__ cursor,
                            int* __restrict__ colb) {
    int e = blockIdx.x * blockDim.x + threadIdx.x;
    if (e >= N_EDGES) return;
    int d = dst[e];
    int pos = atomicAdd(&cursor[d], 1);
    colb[pos] = src[e];
}

// ---------------------------------------------------------------------------
// Kernel: per-node Q/K/V/Skip projections. block 256, one block per node.
__global__ void qkvs_kernel(const float* __restrict__ h, int d,
                            const float* __restrict__ Wq, const float* __restrict__ bq,
                            const float* __restrict__ Wk, const float* __restrict__ bk,
                            const float* __restrict__ Wv, const float* __restrict__ bv,
                            const float* __restrict__ Ws,
                            float* __restrict__ Q, float* __restrict__ K,
                            float* __restrict__ V, float* __restrict__ S) {
    __shared__ float sh[HID];
    int n = blockIdx.x;
    int t = threadIdx.x;
    if (t < d) sh[t] = h[n * d + t];
    __syncthreads();
    int which = t >> 6;
    int j = t & 63;
    const float* W; const float* bias; float* out;
    if (which == 0)      { W = Wq; bias = bq; out = Q; }
    else if (which == 1) { W = Wk; bias = bk; out = K; }
    else if (which == 2) { W = Wv; bias = bv; out = V; }
    else                 { W = Ws; bias = nullptr; out = S; }
    float acc = bias ? bias[j] : 0.0f;
    #pragma unroll 8
    for (int i = 0; i < d; i++) acc = fmaf(sh[i], W[i * 64 + j], acc);
    out[n * 64 + j] = acc;
}

// ---------------------------------------------------------------------------
// Kernel: per-node attention aggregation (online softmax) + skip + LayerNorm
// + optional residual + optional ReLU. One wave per node; lane = head*C + c.
template <int HEADS, bool RES, bool RELU>
__global__ void agg_kernel(const float* __restrict__ Q, const float* __restrict__ K,
                           const float* __restrict__ V, const float* __restrict__ S,
                           const int* __restrict__ row_ptr, const int* __restrict__ colb,
                           const float* __restrict__ g, const float* __restrict__ b,
                           const float* __restrict__ h_in, float* __restrict__ h_out) {
    constexpr int C = HID / HEADS;
    int lane = threadIdx.x & 63;
    int n = blockIdx.x * 4 + (threadIdx.x >> 6);

    float q = Q[n * 64 + lane];
    int beg = row_ptr[n], end = row_ptr[n + 1];

    const float scale = rsqrtf((float)C);
    float m = -1e30f, ssum = 0.0f, acc = 0.0f;

    for (int base = beg; base < end; base += 64) {
        int cnt = min(64, end - base);
        int src_l = (base + lane < end) ? colb[base + lane] : 0;
        for (int j = 0; j < cnt; j++) {
            int src = __shfl(src_l, j);
            float k = K[src * 64 + lane];
            float v = V[src * 64 + lane];
            float t = q * k;
            #pragma unroll
            for (int off = 1; off < C; off <<= 1) t += __shfl_xor(t, off);
            float score = t * scale;
            float nm = fmaxf(m, score);
            float escale = __expf(m - nm);
            float p = __expf(score - nm);
            acc = acc * escale + p * v;
            ssum = ssum * escale + p;
            m = nm;
        }
    }

    float outf = acc / (ssum + 1e-16f) + S[n * 64 + lane];

    float s = outf;
    #pragma unroll
    for (int off = 1; off < 64; off <<= 1) s += __shfl_xor(s, off);
    float mu = s * (1.0f / 64.0f);
    float d = outf - mu;
    float vs = d * d;
    #pragma unroll
    for (int off = 1; off < 64; off <<= 1) vs += __shfl_xor(vs, off);
    float var = vs * (1.0f / 64.0f);
    float y = d * rsqrtf(var + 1e-5f) * g[lane] + b[lane];
    if (RES)  y += 0.1f * h_in[n * 64 + lane];
    if (RELU) y = fmaxf(y, 0.0f);
    h_out[n * 64 + lane] = y;
}

// ---------------------------------------------------------------------------
// Kernel: final two MLP heads. One wave per node.
__global__ void head_kernel(const float* __restrict__ h,
                            const float* __restrict__ Wr1, const float* __restrict__ br1,
                            const float* __restrict__ Wr2, const float* __restrict__ br2,
                            const float* __restrict__ Wt1, const float* __restrict__ bt1,
                            const float* __restrict__ Wt2, const float* __restrict__ bt2,
                            float* __restrict__ out) {
    __shared__ float sh[4][HID];
    int wave = threadIdx.x >> 6;
    int lane = threadIdx.x & 63;
    int n = blockIdx.x * 4 + wave;
    sh[wave][lane] = h[n * 64 + lane];
    __syncthreads();
    int half = lane >> 5;
    int j = lane & 31;
    const float* W1 = half ? Wt1 : Wr1;
    const float* b1 = half ? bt1 : br1;
    const float* W2 = half ? Wt2 : Wr2;
    const float* b2 = half ? bt2 : br2;
    float a = b1[j];
    #pragma unroll 8
    for (int i = 0; i < 64; i++) a = fmaf(sh[wave][i], W1[i * 32 + j], a);
    a = fmaxf(a, 0.0f);
    float r = a * W2[j];
    #pragma unroll
    for (int off = 1; off < 32; off <<= 1) r += __shfl_xor(r, off);
    if (j == 0) out[n * 2 + half] = r + b2[0];
}

// ---------------------------------------------------------------------------
extern "C" void kernel_launch(void* const* d_in, const int* in_sizes, int n_in,
                              void* d_out, int out_size, void* d_ws, size_t ws_size,
                              hipStream_t stream) {
    const float* x    = (const float*)d_in[0];
    const int*   ei   = (const int*)d_in[1];
    const int*   src  = ei;
    const int*   dst  = ei + N_EDGES;
    const float* ln0g = (const float*)d_in[2];
    const float* ln0b = (const float*)d_in[3];

    const float* P[27];
    for (int i = 0; i < 27; i++) P[i] = (const float*)d_in[4 + i];
    const float* Wr1 = (const float*)d_in[31];
    const float* br1 = (const float*)d_in[32];
    const float* Wr2 = (const float*)d_in[33];
    const float* br2 = (const float*)d_in[34];
    const float* Wt1 = (const float*)d_in[35];
    const float* bt1 = (const float*)d_in[36];
    const float* Wt2 = (const float*)d_in[37];
    const float* bt2 = (const float*)d_in[38];

    float* out = (float*)d_out;

    // workspace layout
    float* hbuf0 = (float*)d_ws;                 // N*64
    float* hbuf1 = hbuf0 + N_NODES * 64;         // N*64
    float* Qb    = hbuf1 + N_NODES * 64;
    float* Kb    = Qb + N_NODES * 64;
    float* Vb    = Kb + N_NODES * 64;
    float* Sb    = Vb + N_NODES * 64;
    int* row_ptr = (int*)(Sb + N_NODES * 64);    // N+1
    int* cursor  = row_ptr + (N_NODES + 1);      // N
    int* deg     = cursor + N_NODES;             // N
    int* colb    = deg + N_NODES;                // E
    int* csum    = colb + N_EDGES;               // N_CHUNKS
    int* coff    = csum + N_CHUNKS;              // N_CHUNKS

    // ---- graph structure (rebuilt every launch; ws is re-poisoned) ----
    hipMemsetAsync(deg, 0, N_NODES * sizeof(int), stream);
    ln0_kernel<<<6250, 256, 0, stream>>>(x, ln0g, ln0b, hbuf0);
    deg_kernel<<<(N_EDGES + 255) / 256, 256, 0, stream>>>(dst, deg);
    chunk_sum_kernel<<<N_CHUNKS, 256, 0, stream>>>(deg, csum);
    scan_sums_kernel<<<1, 64, 0, stream>>>(csum, coff, row_ptr);
    scan_final_kernel<<<N_CHUNKS, 256, 0, stream>>>(deg, coff, row_ptr, cursor);
    fill_kernel<<<(N_EDGES + 255) / 256, 256, 0, stream>>>(src, dst, cursor, colb);

    // ---- layer 0: 32 -> 64, heads=4, no residual, relu ----
    qkvs_kernel<<<N_NODES, 256, 0, stream>>>(hbuf0, 32,
        P[0], P[1], P[2], P[3], P[4], P[5], P[6], Qb, Kb, Vb, Sb);
    agg_kernel<4, false, true><<<12500, 256, 0, stream>>>(Qb, Kb, Vb, Sb,
        row_ptr, colb, P[7], P[8], nullptr, hbuf1);

    // ---- layer 1: 64 -> 64, heads=4, residual, relu ----
    qkvs_kernel<<<N_NODES, 256, 0, stream>>>(hbuf1, 64,
        P[9], P[10], P[11], P[12], P[13], P[14], P[15], Qb, Kb, Vb, Sb);
    agg_kernel<4, true, true><<<12500, 256, 0, stream>>>(Qb, Kb, Vb, Sb,
        row_ptr, colb, P[16], P[17], hbuf1, hbuf0);

    // ---- layer 2: 64 -> 64, heads=1, residual, no relu ----
    qkvs_kernel<<<N_NODES, 256, 0, stream>>>(hbuf0, 64,
        P[18], P[19], P[20], P[21], P[22], P[23], P[24], Qb, Kb, Vb, Sb);
    agg_kernel<1, true, false><<<12500, 256, 0, stream>>>(Qb, Kb, Vb, Sb,
        row_ptr, colb, P[25], P[26], hbuf0, hbuf1);

    // ---- MLP heads ----
    head_kernel<<<12500, 256, 0, stream>>>(hbuf1,
        Wr1, br1, Wr2, br2, Wt1, bt1, Wt2, bt2, out);
}

// Round 3
// 648.225 us; speedup vs baseline: 1.7555x; 1.1898x over previous
//
#include <hip/hip_runtime.h>
#include <hip/hip_bf16.h>
#include <math.h>

#define N_NODES 50000
#define N_EDGES 800000
#define HID 64
#define N_CHUNKS ((N_NODES + 255) / 256)   // 196
#define QKVS_TILE 64
#define N_QKVS_BLOCKS ((N_NODES + QKVS_TILE - 1) / QKVS_TILE)  // 782

// ---------------------------------------------------------------------------
// Kernel 1: initial LayerNorm over 32 features. One 32-lane half-wave per node.
__global__ void ln0_kernel(const float* __restrict__ x,
                           const float* __restrict__ g,
                           const float* __restrict__ b,
                           float* __restrict__ h0) {
    int lane = threadIdx.x & 63;
    int n = blockIdx.x * 8 + (threadIdx.x >> 6) * 2 + (lane >> 5);
    int c = lane & 31;
    float v = x[n * 32 + c];
    float s = v;
    #pragma unroll
    for (int off = 1; off < 32; off <<= 1) s += __shfl_xor(s, off);
    float mu = s * (1.0f / 32.0f);
    float d = v - mu;
    float vs = d * d;
    #pragma unroll
    for (int off = 1; off < 32; off <<= 1) vs += __shfl_xor(vs, off);
    float var = vs * (1.0f / 32.0f);
    float y = d * rsqrtf(var + 1e-5f) * g[c] + b[c];
    h0[n * 32 + c] = y;
}

// ---------------------------------------------------------------------------
// CSR build: degree count, 3-phase hierarchical exclusive scan, scatter fill.
__global__ void deg_kernel(const int* __restrict__ dst, int* __restrict__ deg) {
    int e = blockIdx.x * blockDim.x + threadIdx.x;
    if (e >= N_EDGES) return;
    atomicAdd(&deg[dst[e]], 1);
}

__global__ void chunk_sum_kernel(const int* __restrict__ deg, int* __restrict__ csum) {
    int i = blockIdx.x * 256 + threadIdx.x;
    int v = (i < N_NODES) ? deg[i] : 0;
    #pragma unroll
    for (int off = 1; off < 64; off <<= 1) v += __shfl_xor(v, off);
    __shared__ int ws[4];
    if ((threadIdx.x & 63) == 0) ws[threadIdx.x >> 6] = v;
    __syncthreads();
    if (threadIdx.x == 0) csum[blockIdx.x] = ws[0] + ws[1] + ws[2] + ws[3];
}

__global__ void scan_sums_kernel(const int* __restrict__ csum,
                                 int* __restrict__ coff,
                                 int* __restrict__ row_ptr) {
    int lane = threadIdx.x;
    int carry = 0;
    for (int base = 0; base < N_CHUNKS; base += 64) {
        int i = base + lane;
        int v = (i < N_CHUNKS) ? csum[i] : 0;
        int incl = v;
        #pragma unroll
        for (int off = 1; off < 64; off <<= 1) {
            int t = __shfl_up(incl, off);
            if (lane >= off) incl += t;
        }
        if (i < N_CHUNKS) coff[i] = carry + incl - v;
        carry += __shfl(incl, 63);
    }
    if (lane == 0) row_ptr[N_NODES] = carry;
}

__global__ void scan_final_kernel(const int* __restrict__ deg,
                                  const int* __restrict__ coff,
                                  int* __restrict__ row_ptr,
                                  int* __restrict__ cursor) {
    int i = blockIdx.x * 256 + threadIdx.x;
    int lane = threadIdx.x & 63;
    int w = threadIdx.x >> 6;
    int v = (i < N_NODES) ? deg[i] : 0;
    int incl = v;
    #pragma unroll
    for (int off = 1; off < 64; off <<= 1) {
        int t = __shfl_up(incl, off);
        if (lane >= off) incl += t;
    }
    __shared__ int ws[4];
    if (lane == 63) ws[w] = incl;
    __syncthreads();
    int woff = 0;
    #pragma unroll
    for (int k = 0; k < 4; k++) if (k < w) woff += ws[k];
    int excl = coff[blockIdx.x] + woff + incl - v;
    if (i < N_NODES) { row_ptr[i] = excl; cursor[i] = excl; }
}

__global__ void fill_kernel(const int* __restrict__ src,
                            const int* __restrict__ dst,
                            int* __restrict__ cursor,
                            int* __restrict__ colb) {
    int e = blockIdx.x * blockDim.x + threadIdx.x;
    if (e >= N_EDGES) return;
    int d = dst[e];
    int pos = atomicAdd(&cursor[d], 1);
    colb[pos] = src[e];
}

// ---------------------------------------------------------------------------
// Kernel: Q/K/V/Skip projections, register-blocked skinny GEMM.
// Block = 64 nodes. Thread (which = t>>6, j = t&63) keeps its 64-entry weight
// column in VGPRs (loaded once per block); h tile staged in LDS; inner loop is
// float4 LDS broadcasts + register FMAs, 2 nodes in flight for ILP.
template <int D>
__global__ __launch_bounds__(256) void qkvs_kernel(
                            const float* __restrict__ h,
                            const float* __restrict__ Wq, const float* __restrict__ bq,
                            const float* __restrict__ Wk, const float* __restrict__ bk,
                            const float* __restrict__ Wv, const float* __restrict__ bv,
                            const float* __restrict__ Ws,
                            float* __restrict__ Q, float* __restrict__ K,
                            float* __restrict__ V, float* __restrict__ S) {
    __shared__ float sh[QKVS_TILE][D];
    int t = threadIdx.x;
    int n0 = blockIdx.x * QKVS_TILE;
    int cnt = min(QKVS_TILE, N_NODES - n0);

    // cooperative coalesced load of the h tile
    for (int idx = t; idx < cnt * D; idx += 256)
        sh[idx / D][idx % D] = h[n0 * D + idx];

    int which = t >> 6;
    int j = t & 63;
    const float* W    = (which == 0) ? Wq : (which == 1) ? Wk : (which == 2) ? Wv : Ws;
    const float* bias = (which == 0) ? bq : (which == 1) ? bk : (which == 2) ? bv : nullptr;
    float*       out  = (which == 0) ? Q  : (which == 1) ? K  : (which == 2) ? V  : S;

    float wcol[D];
    #pragma unroll
    for (int i = 0; i < D; i++) wcol[i] = W[i * 64 + j];
    float bj = (which == 3) ? 0.0f : bias[j];

    __syncthreads();

    for (int n = 0; n < cnt; n += 2) {
        float acc0 = bj, acc1 = bj;
        const float4* r0 = (const float4*)sh[n];
        const float4* r1 = (const float4*)sh[n + 1];
        #pragma unroll
        for (int i4 = 0; i4 < D / 4; i4++) {
            float4 h0 = r0[i4];
            float4 h1 = r1[i4];
            acc0 = fmaf(h0.x, wcol[4 * i4 + 0], acc0);
            acc1 = fmaf(h1.x, wcol[4 * i4 + 0], acc1);
            acc0 = fmaf(h0.y, wcol[4 * i4 + 1], acc0);
            acc1 = fmaf(h1.y, wcol[4 * i4 + 1], acc1);
            acc0 = fmaf(h0.z, wcol[4 * i4 + 2], acc0);
            acc1 = fmaf(h1.z, wcol[4 * i4 + 2], acc1);
            acc0 = fmaf(h0.w, wcol[4 * i4 + 3], acc0);
            acc1 = fmaf(h1.w, wcol[4 * i4 + 3], acc1);
        }
        out[(n0 + n) * 64 + j] = acc0;
        out[(n0 + n + 1) * 64 + j] = acc1;
    }
}

// ---------------------------------------------------------------------------
// Kernel: per-node attention aggregation (online softmax) + skip + LayerNorm
// + optional residual + optional ReLU. One wave per node; lane = head*C + c.
template <int HEADS, bool RES, bool RELU>
__global__ void agg_kernel(const float* __restrict__ Q, const float* __restrict__ K,
                           const float* __restrict__ V, const float* __restrict__ S,
                           const int* __restrict__ row_ptr, const int* __restrict__ colb,
                           const float* __restrict__ g, const float* __restrict__ b,
                           const float* __restrict__ h_in, float* __restrict__ h_out) {
    constexpr int C = HID / HEADS;
    int lane = threadIdx.x & 63;
    int n = blockIdx.x * 4 + (threadIdx.x >> 6);

    float q = Q[n * 64 + lane];
    int beg = row_ptr[n], end = row_ptr[n + 1];

    const float scale = rsqrtf((float)C);
    float m = -1e30f, ssum = 0.0f, acc = 0.0f;

    for (int base = beg; base < end; base += 64) {
        int cnt = min(64, end - base);
        int src_l = (base + lane < end) ? colb[base + lane] : 0;
        for (int j = 0; j < cnt; j++) {
            int src = __shfl(src_l, j);
            float k = K[src * 64 + lane];
            float v = V[src * 64 + lane];
            float t = q * k;
            #pragma unroll
            for (int off = 1; off < C; off <<= 1) t += __shfl_xor(t, off);
            float score = t * scale;
            float nm = fmaxf(m, score);
            float escale = __expf(m - nm);
            float p = __expf(score - nm);
            acc = acc * escale + p * v;
            ssum = ssum * escale + p;
            m = nm;
        }
    }

    float outf = acc / (ssum + 1e-16f) + S[n * 64 + lane];

    float s = outf;
    #pragma unroll
    for (int off = 1; off < 64; off <<= 1) s += __shfl_xor(s, off);
    float mu = s * (1.0f / 64.0f);
    float d = outf - mu;
    float vs = d * d;
    #pragma unroll
    for (int off = 1; off < 64; off <<= 1) vs += __shfl_xor(vs, off);
    float var = vs * (1.0f / 64.0f);
    float y = d * rsqrtf(var + 1e-5f) * g[lane] + b[lane];
    if (RES)  y += 0.1f * h_in[n * 64 + lane];
    if (RELU) y = fmaxf(y, 0.0f);
    h_out[n * 64 + lane] = y;
}

// ---------------------------------------------------------------------------
// Kernel: final two MLP heads. One wave per node.
__global__ void head_kernel(const float* __restrict__ h,
                            const float* __restrict__ Wr1, const float* __restrict__ br1,
                            const float* __restrict__ Wr2, const float* __restrict__ br2,
                            const float* __restrict__ Wt1, const float* __restrict__ bt1,
                            const float* __restrict__ Wt2, const float* __restrict__ bt2,
                            float* __restrict__ out) {
    __shared__ float sh[4][HID];
    int wave = threadIdx.x >> 6;
    int lane = threadIdx.x & 63;
    int n = blockIdx.x * 4 + wave;
    sh[wave][lane] = h[n * 64 + lane];
    __syncthreads();
    int half = lane >> 5;
    int j = lane & 31;
    const float* W1 = half ? Wt1 : Wr1;
    const float* b1 = half ? bt1 : br1;
    const float* W2 = half ? Wt2 : Wr2;
    const float* b2 = half ? bt2 : br2;
    float a = b1[j];
    #pragma unroll 8
    for (int i = 0; i < 64; i++) a = fmaf(sh[wave][i], W1[i * 32 + j], a);
    a = fmaxf(a, 0.0f);
    float r = a * W2[j];
    #pragma unroll
    for (int off = 1; off < 32; off <<= 1) r += __shfl_xor(r, off);
    if (j == 0) out[n * 2 + half] = r + b2[0];
}

// ---------------------------------------------------------------------------
extern "C" void kernel_launch(void* const* d_in, const int* in_sizes, int n_in,
                              void* d_out, int out_size, void* d_ws, size_t ws_size,
                              hipStream_t stream) {
    const float* x    = (const float*)d_in[0];
    const int*   ei   = (const int*)d_in[1];
    const int*   src  = ei;
    const int*   dst  = ei + N_EDGES;
    const float* ln0g = (const float*)d_in[2];
    const float* ln0b = (const float*)d_in[3];

    const float* P[27];
    for (int i = 0; i < 27; i++) P[i] = (const float*)d_in[4 + i];
    const float* Wr1 = (const float*)d_in[31];
    const float* br1 = (const float*)d_in[32];
    const float* Wr2 = (const float*)d_in[33];
    const float* br2 = (const float*)d_in[34];
    const float* Wt1 = (const float*)d_in[35];
    const float* bt1 = (const float*)d_in[36];
    const float* Wt2 = (const float*)d_in[37];
    const float* bt2 = (const float*)d_in[38];

    float* out = (float*)d_out;

    // workspace layout
    float* hbuf0 = (float*)d_ws;                 // N*64
    float* hbuf1 = hbuf0 + N_NODES * 64;         // N*64
    float* Qb    = hbuf1 + N_NODES * 64;
    float* Kb    = Qb + N_NODES * 64;
    float* Vb    = Kb + N_NODES * 64;
    float* Sb    = Vb + N_NODES * 64;
    int* row_ptr = (int*)(Sb + N_NODES * 64);    // N+1
    int* cursor  = row_ptr + (N_NODES + 1);      // N
    int* deg     = cursor + N_NODES;             // N
    int* colb    = deg + N_NODES;                // E
    int* csum    = colb + N_EDGES;               // N_CHUNKS
    int* coff    = csum + N_CHUNKS;              // N_CHUNKS

    // ---- graph structure (rebuilt every launch; ws is re-poisoned) ----
    hipMemsetAsync(deg, 0, N_NODES * sizeof(int), stream);
    ln0_kernel<<<6250, 256, 0, stream>>>(x, ln0g, ln0b, hbuf0);
    deg_kernel<<<(N_EDGES + 255) / 256, 256, 0, stream>>>(dst, deg);
    chunk_sum_kernel<<<N_CHUNKS, 256, 0, stream>>>(deg, csum);
    scan_sums_kernel<<<1, 64, 0, stream>>>(csum, coff, row_ptr);
    scan_final_kernel<<<N_CHUNKS, 256, 0, stream>>>(deg, coff, row_ptr, cursor);
    fill_kernel<<<(N_EDGES + 255) / 256, 256, 0, stream>>>(src, dst, cursor, colb);

    // ---- layer 0: 32 -> 64, heads=4, no residual, relu ----
    qkvs_kernel<32><<<N_QKVS_BLOCKS, 256, 0, stream>>>(hbuf0,
        P[0], P[1], P[2], P[3], P[4], P[5], P[6], Qb, Kb, Vb, Sb);
    agg_kernel<4, false, true><<<12500, 256, 0, stream>>>(Qb, Kb, Vb, Sb,
        row_ptr, colb, P[7], P[8], nullptr, hbuf1);

    // ---- layer 1: 64 -> 64, heads=4, residual, relu ----
    qkvs_kernel<64><<<N_QKVS_BLOCKS, 256, 0, stream>>>(hbuf1,
        P[9], P[10], P[11], P[12], P[13], P[14], P[15], Qb, Kb, Vb, Sb);
    agg_kernel<4, true, true><<<12500, 256, 0, stream>>>(Qb, Kb, Vb, Sb,
        row_ptr, colb, P[16], P[17], hbuf1, hbuf0);

    // ---- layer 2: 64 -> 64, heads=1, residual, no relu ----
    qkvs_kernel<64><<<N_QKVS_BLOCKS, 256, 0, stream>>>(hbuf0,
        P[18], P[19], P[20], P[21], P[22], P[23], P[24], Qb, Kb, Vb, Sb);
    agg_kernel<1, true, false><<<12500, 256, 0, stream>>>(Qb, Kb, Vb, Sb,
        row_ptr, colb, P[25], P[26], hbuf0, hbuf1);

    // ---- MLP heads ----
    head_kernel<<<12500, 256, 0, stream>>>(hbuf1,
        Wr1, br1, Wr2, br2, Wt1, bt1, Wt2, bt2, out);
}

// Round 4
// 538.487 us; speedup vs baseline: 2.1133x; 1.2038x over previous
//
#include <hip/hip_runtime.h>
#include <hip/hip_bf16.h>
#include <math.h>

#define N_NODES 50000
#define N_EDGES 800000
#define HID 64
#define N_CHUNKS ((N_NODES + 255) / 256)   // 196
#define QKVS_TILE 64
#define N_QKVS_BLOCKS ((N_NODES + QKVS_TILE - 1) / QKVS_TILE)  // 782

// ---------------------------------------------------------------------------
// Kernel 1: initial LayerNorm over 32 features. One 32-lane half-wave per node.
__global__ void ln0_kernel(const float* __restrict__ x,
                           const float* __restrict__ g,
                           const float* __restrict__ b,
                           float* __restrict__ h0) {
    int lane = threadIdx.x & 63;
    int n = blockIdx.x * 8 + (threadIdx.x >> 6) * 2 + (lane >> 5);
    int c = lane & 31;
    float v = x[n * 32 + c];
    float s = v;
    #pragma unroll
    for (int off = 1; off < 32; off <<= 1) s += __shfl_xor(s, off);
    float mu = s * (1.0f / 32.0f);
    float d = v - mu;
    float vs = d * d;
    #pragma unroll
    for (int off = 1; off < 32; off <<= 1) vs += __shfl_xor(vs, off);
    float var = vs * (1.0f / 32.0f);
    float y = d * rsqrtf(var + 1e-5f) * g[c] + b[c];
    h0[n * 32 + c] = y;
}

// ---------------------------------------------------------------------------
// CSR build: degree count, 3-phase hierarchical exclusive scan, scatter fill.
__global__ void deg_kernel(const int* __restrict__ dst, int* __restrict__ deg) {
    int e = blockIdx.x * blockDim.x + threadIdx.x;
    if (e >= N_EDGES) return;
    atomicAdd(&deg[dst[e]], 1);
}

__global__ void chunk_sum_kernel(const int* __restrict__ deg, int* __restrict__ csum) {
    int i = blockIdx.x * 256 + threadIdx.x;
    int v = (i < N_NODES) ? deg[i] : 0;
    #pragma unroll
    for (int off = 1; off < 64; off <<= 1) v += __shfl_xor(v, off);
    __shared__ int ws[4];
    if ((threadIdx.x & 63) == 0) ws[threadIdx.x >> 6] = v;
    __syncthreads();
    if (threadIdx.x == 0) csum[blockIdx.x] = ws[0] + ws[1] + ws[2] + ws[3];
}

__global__ void scan_sums_kernel(const int* __restrict__ csum,
                                 int* __restrict__ coff,
                                 int* __restrict__ row_ptr) {
    int lane = threadIdx.x;
    int carry = 0;
    for (int base = 0; base < N_CHUNKS; base += 64) {
        int i = base + lane;
        int v = (i < N_CHUNKS) ? csum[i] : 0;
        int incl = v;
        #pragma unroll
        for (int off = 1; off < 64; off <<= 1) {
            int t = __shfl_up(incl, off);
            if (lane >= off) incl += t;
        }
        if (i < N_CHUNKS) coff[i] = carry + incl - v;
        carry += __shfl(incl, 63);
    }
    if (lane == 0) row_ptr[N_NODES] = carry;
}

__global__ void scan_final_kernel(const int* __restrict__ deg,
                                  const int* __restrict__ coff,
                                  int* __restrict__ row_ptr,
                                  int* __restrict__ cursor) {
    int i = blockIdx.x * 256 + threadIdx.x;
    int lane = threadIdx.x & 63;
    int w = threadIdx.x >> 6;
    int v = (i < N_NODES) ? deg[i] : 0;
    int incl = v;
    #pragma unroll
    for (int off = 1; off < 64; off <<= 1) {
        int t = __shfl_up(incl, off);
        if (lane >= off) incl += t;
    }
    __shared__ int ws[4];
    if (lane == 63) ws[w] = incl;
    __syncthreads();
    int woff = 0;
    #pragma unroll
    for (int k = 0; k < 4; k++) if (k < w) woff += ws[k];
    int excl = coff[blockIdx.x] + woff + incl - v;
    if (i < N_NODES) { row_ptr[i] = excl; cursor[i] = excl; }
}

__global__ void fill_kernel(const int* __restrict__ src,
                            const int* __restrict__ dst,
                            int* __restrict__ cursor,
                            int* __restrict__ colb) {
    int e = blockIdx.x * blockDim.x + threadIdx.x;
    if (e >= N_EDGES) return;
    int d = dst[e];
    int pos = atomicAdd(&cursor[d], 1);
    colb[pos] = src[e];
}

// ---------------------------------------------------------------------------
// Kernel: Q/K/V/Skip projections, register-blocked skinny GEMM.
// K and V are written interleaved into KV: KV[n*128 + 2c] = K[n][c],
// KV[n*128 + 2c+1] = V[n][c]  -> agg gathers one float2 per edge per lane.
template <int D>
__global__ __launch_bounds__(256) void qkvs_kernel(
                            const float* __restrict__ h,
                            const float* __restrict__ Wq, const float* __restrict__ bq,
                            const float* __restrict__ Wk, const float* __restrict__ bk,
                            const float* __restrict__ Wv, const float* __restrict__ bv,
                            const float* __restrict__ Ws,
                            float* __restrict__ Q, float* __restrict__ KV,
                            float* __restrict__ S) {
    __shared__ float sh[QKVS_TILE][D];
    int t = threadIdx.x;
    int n0 = blockIdx.x * QKVS_TILE;
    int cnt = min(QKVS_TILE, N_NODES - n0);

    for (int idx = t; idx < cnt * D; idx += 256)
        sh[idx / D][idx % D] = h[n0 * D + idx];

    int which = t >> 6;
    int j = t & 63;
    const float* W    = (which == 0) ? Wq : (which == 1) ? Wk : (which == 2) ? Wv : Ws;
    const float* bias = (which == 0) ? bq : (which == 1) ? bk : (which == 2) ? bv : nullptr;
    float* out; int stride; int off;
    if (which == 0)      { out = Q;  stride = 64;  off = j; }
    else if (which == 1) { out = KV; stride = 128; off = 2 * j; }
    else if (which == 2) { out = KV; stride = 128; off = 2 * j + 1; }
    else                 { out = S;  stride = 64;  off = j; }

    float wcol[D];
    #pragma unroll
    for (int i = 0; i < D; i++) wcol[i] = W[i * 64 + j];
    float bj = (which == 3) ? 0.0f : bias[j];

    __syncthreads();

    for (int n = 0; n < cnt; n += 2) {
        float acc0 = bj, acc1 = bj;
        const float4* r0 = (const float4*)sh[n];
        const float4* r1 = (const float4*)sh[n + 1];
        #pragma unroll
        for (int i4 = 0; i4 < D / 4; i4++) {
            float4 h0 = r0[i4];
            float4 h1 = r1[i4];
            acc0 = fmaf(h0.x, wcol[4 * i4 + 0], acc0);
            acc1 = fmaf(h1.x, wcol[4 * i4 + 0], acc1);
            acc0 = fmaf(h0.y, wcol[4 * i4 + 1], acc0);
            acc1 = fmaf(h1.y, wcol[4 * i4 + 1], acc1);
            acc0 = fmaf(h0.z, wcol[4 * i4 + 2], acc0);
            acc1 = fmaf(h1.z, wcol[4 * i4 + 2], acc1);
            acc0 = fmaf(h0.w, wcol[4 * i4 + 3], acc0);
            acc1 = fmaf(h1.w, wcol[4 * i4 + 3], acc1);
        }
        out[(n0 + n) * stride + off] = acc0;
        out[(n0 + n + 1) * stride + off] = acc1;
    }
}

// ---------------------------------------------------------------------------
// Kernel: per-node attention aggregation + skip + LayerNorm (+res/relu).
// One wave per node. No max-subtraction (scores are O(3); exp is fp32-safe
// and alpha = exp(s)/sum exp(s) is algebraically identical to the ref).
// 4-edge unroll, two accumulator pairs, scalar (readlane) row bases.
template <int HEADS, bool RES, bool RELU>
__global__ __launch_bounds__(256) void agg_kernel(
                           const float* __restrict__ Q, const float* __restrict__ KV,
                           const float* __restrict__ S,
                           const int* __restrict__ row_ptr, const int* __restrict__ colb,
                           const float* __restrict__ g, const float* __restrict__ b,
                           const float* __restrict__ h_in, float* __restrict__ h_out) {
    constexpr int C = HID / HEADS;
    int lane = threadIdx.x & 63;
    int n = blockIdx.x * 4 + (threadIdx.x >> 6);

    const float scale = rsqrtf((float)C);
    float q = Q[n * 64 + lane] * scale;          // fold 1/sqrt(C) into q
    float sval = S[n * 64 + lane];
    float resv = RES ? h_in[n * 64 + lane] : 0.0f;
    int beg = row_ptr[n], end = row_ptr[n + 1];

    const float2* __restrict__ KV2 = (const float2*)KV;   // row = 64 float2

    float ssumA = 0.0f, accA = 0.0f, ssumB = 0.0f, accB = 0.0f;

    for (int base = beg; base < end; base += 64) {
        int cnt = min(64, end - base);
        int src_l = (base + lane < end) ? colb[base + lane] : 0;
        int j = 0;
        for (; j + 4 <= cnt; j += 4) {
            int s0 = __builtin_amdgcn_readlane(src_l, j);
            int s1 = __builtin_amdgcn_readlane(src_l, j + 1);
            int s2 = __builtin_amdgcn_readlane(src_l, j + 2);
            int s3 = __builtin_amdgcn_readlane(src_l, j + 3);
            float2 kv0 = KV2[(size_t)s0 * 64 + lane];
            float2 kv1 = KV2[(size_t)s1 * 64 + lane];
            float2 kv2 = KV2[(size_t)s2 * 64 + lane];
            float2 kv3 = KV2[(size_t)s3 * 64 + lane];
            float t0 = q * kv0.x, t1 = q * kv1.x, t2 = q * kv2.x, t3 = q * kv3.x;
            #pragma unroll
            for (int off = 1; off < C; off <<= 1) {
                t0 += __shfl_xor(t0, off);
                t1 += __shfl_xor(t1, off);
                t2 += __shfl_xor(t2, off);
                t3 += __shfl_xor(t3, off);
            }
            float p0 = __expf(t0), p1 = __expf(t1);
            float p2 = __expf(t2), p3 = __expf(t3);
            ssumA += p0; accA = fmaf(p0, kv0.y, accA);
            ssumB += p1; accB = fmaf(p1, kv1.y, accB);
            ssumA += p2; accA = fmaf(p2, kv2.y, accA);
            ssumB += p3; accB = fmaf(p3, kv3.y, accB);
        }
        for (; j < cnt; j++) {
            int s0 = __builtin_amdgcn_readlane(src_l, j);
            float2 kv0 = KV2[(size_t)s0 * 64 + lane];
            float t0 = q * kv0.x;
            #pragma unroll
            for (int off = 1; off < C; off <<= 1) t0 += __shfl_xor(t0, off);
            float p0 = __expf(t0);
            ssumA += p0; accA = fmaf(p0, kv0.y, accA);
        }
    }

    float outf = (accA + accB) / ((ssumA + ssumB) + 1e-16f) + sval;

    float s = outf;
    #pragma unroll
    for (int off = 1; off < 64; off <<= 1) s += __shfl_xor(s, off);
    float mu = s * (1.0f / 64.0f);
    float d = outf - mu;
    float vs = d * d;
    #pragma unroll
    for (int off = 1; off < 64; off <<= 1) vs += __shfl_xor(vs, off);
    float var = vs * (1.0f / 64.0f);
    float y = d * rsqrtf(var + 1e-5f) * g[lane] + b[lane];
    if (RES)  y += 0.1f * resv;
    if (RELU) y = fmaxf(y, 0.0f);
    h_out[n * 64 + lane] = y;
}

// ---------------------------------------------------------------------------
// Kernel: final two MLP heads. One wave per node.
__global__ void head_kernel(const float* __restrict__ h,
                            const float* __restrict__ Wr1, const float* __restrict__ br1,
                            const float* __restrict__ Wr2, const float* __restrict__ br2,
                            const float* __restrict__ Wt1, const float* __restrict__ bt1,
                            const float* __restrict__ Wt2, const float* __restrict__ bt2,
                            float* __restrict__ out) {
    __shared__ float sh[4][HID];
    int wave = threadIdx.x >> 6;
    int lane = threadIdx.x & 63;
    int n = blockIdx.x * 4 + wave;
    sh[wave][lane] = h[n * 64 + lane];
    __syncthreads();
    int half = lane >> 5;
    int j = lane & 31;
    const float* W1 = half ? Wt1 : Wr1;
    const float* b1 = half ? bt1 : br1;
    const float* W2 = half ? Wt2 : Wr2;
    const float* b2 = half ? bt2 : br2;
    float a = b1[j];
    #pragma unroll 8
    for (int i = 0; i < 64; i++) a = fmaf(sh[wave][i], W1[i * 32 + j], a);
    a = fmaxf(a, 0.0f);
    float r = a * W2[j];
    #pragma unroll
    for (int off = 1; off < 32; off <<= 1) r += __shfl_xor(r, off);
    if (j == 0) out[n * 2 + half] = r + b2[0];
}

// ---------------------------------------------------------------------------
extern "C" void kernel_launch(void* const* d_in, const int* in_sizes, int n_in,
                              void* d_out, int out_size, void* d_ws, size_t ws_size,
                              hipStream_t stream) {
    const float* x    = (const float*)d_in[0];
    const int*   ei   = (const int*)d_in[1];
    const int*   src  = ei;
    const int*   dst  = ei + N_EDGES;
    const float* ln0g = (const float*)d_in[2];
    const float* ln0b = (const float*)d_in[3];

    const float* P[27];
    for (int i = 0; i < 27; i++) P[i] = (const float*)d_in[4 + i];
    const float* Wr1 = (const float*)d_in[31];
    const float* br1 = (const float*)d_in[32];
    const float* Wr2 = (const float*)d_in[33];
    const float* br2 = (const float*)d_in[34];
    const float* Wt1 = (const float*)d_in[35];
    const float* bt1 = (const float*)d_in[36];
    const float* Wt2 = (const float*)d_in[37];
    const float* bt2 = (const float*)d_in[38];

    float* out = (float*)d_out;

    // workspace layout
    float* hbuf0 = (float*)d_ws;                 // N*64
    float* hbuf1 = hbuf0 + N_NODES * 64;         // N*64
    float* Qb    = hbuf1 + N_NODES * 64;         // N*64
    float* Sb    = Qb + N_NODES * 64;            // N*64
    float* KVb   = Sb + N_NODES * 64;            // N*128
    int* row_ptr = (int*)(KVb + N_NODES * 128);  // N+1
    int* cursor  = row_ptr + (N_NODES + 1);      // N
    int* deg     = cursor + N_NODES;             // N
    int* colb    = deg + N_NODES;                // E
    int* csum    = colb + N_EDGES;               // N_CHUNKS
    int* coff    = csum + N_CHUNKS;              // N_CHUNKS

    // ---- graph structure (rebuilt every launch; ws is re-poisoned) ----
    hipMemsetAsync(deg, 0, N_NODES * sizeof(int), stream);
    ln0_kernel<<<6250, 256, 0, stream>>>(x, ln0g, ln0b, hbuf0);
    deg_kernel<<<(N_EDGES + 255) / 256, 256, 0, stream>>>(dst, deg);
    chunk_sum_kernel<<<N_CHUNKS, 256, 0, stream>>>(deg, csum);
    scan_sums_kernel<<<1, 64, 0, stream>>>(csum, coff, row_ptr);
    scan_final_kernel<<<N_CHUNKS, 256, 0, stream>>>(deg, coff, row_ptr, cursor);
    fill_kernel<<<(N_EDGES + 255) / 256, 256, 0, stream>>>(src, dst, cursor, colb);

    // ---- layer 0: 32 -> 64, heads=4, no residual, relu ----
    qkvs_kernel<32><<<N_QKVS_BLOCKS, 256, 0, stream>>>(hbuf0,
        P[0], P[1], P[2], P[3], P[4], P[5], P[6], Qb, KVb, Sb);
    agg_kernel<4, false, true><<<12500, 256, 0, stream>>>(Qb, KVb, Sb,
        row_ptr, colb, P[7], P[8], nullptr, hbuf1);

    // ---- layer 1: 64 -> 64, heads=4, residual, relu ----
    qkvs_kernel<64><<<N_QKVS_BLOCKS, 256, 0, stream>>>(hbuf1,
        P[9], P[10], P[11], P[12], P[13], P[14], P[15], Qb, KVb, Sb);
    agg_kernel<4, true, true><<<12500, 256, 0, stream>>>(Qb, KVb, Sb,
        row_ptr, colb, P[16], P[17], hbuf1, hbuf0);

    // ---- layer 2: 64 -> 64, heads=1, residual, no relu ----
    qkvs_kernel<64><<<N_QKVS_BLOCKS, 256, 0, stream>>>(hbuf0,
        P[18], P[19], P[20], P[21], P[22], P[23], P[24], Qb, KVb, Sb);
    agg_kernel<1, true, false><<<12500, 256, 0, stream>>>(Qb, KVb, Sb,
        row_ptr, colb, P[25], P[26], hbuf0, hbuf1);

    // ---- MLP heads ----
    head_kernel<<<12500, 256, 0, stream>>>(hbuf1,
        Wr1, br1, Wr2, br2, Wt1, bt1, Wt2, bt2, out);
}

// Round 5
// 515.777 us; speedup vs baseline: 2.2063x; 1.0440x over previous
//
#include <hip/hip_runtime.h>
#include <hip/hip_bf16.h>
#include <math.h>

#define N_NODES 50000
#define N_EDGES 800000
#define HID 64
#define N_CHUNKS ((N_NODES + 255) / 256)   // 196
#define QKVS_TILE 64
#define N_QKVS_BLOCKS ((N_NODES + QKVS_TILE - 1) / QKVS_TILE)  // 782

__device__ __forceinline__ unsigned short f32_to_bf16_rne(float f) {
    unsigned int u = __float_as_uint(f);
    unsigned int r = u + 0x7fffu + ((u >> 16) & 1u);
    return (unsigned short)(r >> 16);
}

// ---------------------------------------------------------------------------
// Kernel 1: initial LayerNorm over 32 features. One 32-lane half-wave per node.
__global__ void ln0_kernel(const float* __restrict__ x,
                           const float* __restrict__ g,
                           const float* __restrict__ b,
                           float* __restrict__ h0) {
    int lane = threadIdx.x & 63;
    int n = blockIdx.x * 8 + (threadIdx.x >> 6) * 2 + (lane >> 5);
    int c = lane & 31;
    float v = x[n * 32 + c];
    float s = v;
    #pragma unroll
    for (int off = 1; off < 32; off <<= 1) s += __shfl_xor(s, off);
    float mu = s * (1.0f / 32.0f);
    float d = v - mu;
    float vs = d * d;
    #pragma unroll
    for (int off = 1; off < 32; off <<= 1) vs += __shfl_xor(vs, off);
    float var = vs * (1.0f / 32.0f);
    float y = d * rsqrtf(var + 1e-5f) * g[c] + b[c];
    h0[n * 32 + c] = y;
}

// ---------------------------------------------------------------------------
// CSR build: degree count, 3-phase hierarchical exclusive scan, scatter fill.
__global__ void deg_kernel(const int* __restrict__ dst, int* __restrict__ deg) {
    int e = blockIdx.x * blockDim.x + threadIdx.x;
    if (e >= N_EDGES) return;
    atomicAdd(&deg[dst[e]], 1);
}

__global__ void chunk_sum_kernel(const int* __restrict__ deg, int* __restrict__ csum) {
    int i = blockIdx.x * 256 + threadIdx.x;
    int v = (i < N_NODES) ? deg[i] : 0;
    #pragma unroll
    for (int off = 1; off < 64; off <<= 1) v += __shfl_xor(v, off);
    __shared__ int ws[4];
    if ((threadIdx.x & 63) == 0) ws[threadIdx.x >> 6] = v;
    __syncthreads();
    if (threadIdx.x == 0) csum[blockIdx.x] = ws[0] + ws[1] + ws[2] + ws[3];
}

__global__ void scan_sums_kernel(const int* __restrict__ csum,
                                 int* __restrict__ coff,
                                 int* __restrict__ row_ptr) {
    int lane = threadIdx.x;
    int carry = 0;
    for (int base = 0; base < N_CHUNKS; base += 64) {
        int i = base + lane;
        int v = (i < N_CHUNKS) ? csum[i] : 0;
        int incl = v;
        #pragma unroll
        for (int off = 1; off < 64; off <<= 1) {
            int t = __shfl_up(incl, off);
            if (lane >= off) incl += t;
        }
        if (i < N_CHUNKS) coff[i] = carry + incl - v;
        carry += __shfl(incl, 63);
    }
    if (lane == 0) row_ptr[N_NODES] = carry;
}

__global__ void scan_final_kernel(const int* __restrict__ deg,
                                  const int* __restrict__ coff,
                                  int* __restrict__ row_ptr,
                                  int* __restrict__ cursor) {
    int i = blockIdx.x * 256 + threadIdx.x;
    int lane = threadIdx.x & 63;
    int w = threadIdx.x >> 6;
    int v = (i < N_NODES) ? deg[i] : 0;
    int incl = v;
    #pragma unroll
    for (int off = 1; off < 64; off <<= 1) {
        int t = __shfl_up(incl, off);
        if (lane >= off) incl += t;
    }
    __shared__ int ws[4];
    if (lane == 63) ws[w] = incl;
    __syncthreads();
    int woff = 0;
    #pragma unroll
    for (int k = 0; k < 4; k++) if (k < w) woff += ws[k];
    int excl = coff[blockIdx.x] + woff + incl - v;
    if (i < N_NODES) { row_ptr[i] = excl; cursor[i] = excl; }
}

__global__ void fill_kernel(const int* __restrict__ src,
                            const int* __restrict__ dst,
                            int* __restrict__ cursor,
                            int* __restrict__ colb) {
    int e = blockIdx.x * blockDim.x + threadIdx.x;
    if (e >= N_EDGES) return;
    int d = dst[e];
    int pos = atomicAdd(&cursor[d], 1);
    colb[pos] = src[e];
}

// ---------------------------------------------------------------------------
// Kernel: Q/K/V/Skip projections, register-blocked skinny GEMM.
// K and V are written as bf16 packed into one dword per channel:
// KV[n*64 + c] = (bf16(V[n][c]) << 16) | bf16(K[n][c])
// -> agg gathers ONE dword per edge per lane (256 B/row).
template <int D>
__global__ __launch_bounds__(256) void qkvs_kernel(
                            const float* __restrict__ h,
                            const float* __restrict__ Wq, const float* __restrict__ bq,
                            const float* __restrict__ Wk, const float* __restrict__ bk,
                            const float* __restrict__ Wv, const float* __restrict__ bv,
                            const float* __restrict__ Ws,
                            float* __restrict__ Q, unsigned int* __restrict__ KV,
                            float* __restrict__ S) {
    __shared__ float sh[QKVS_TILE][D];
    int t = threadIdx.x;
    int n0 = blockIdx.x * QKVS_TILE;
    int cnt = min(QKVS_TILE, N_NODES - n0);

    for (int idx = t; idx < cnt * D; idx += 256)
        sh[idx / D][idx % D] = h[n0 * D + idx];

    int which = t >> 6;
    int j = t & 63;
    const float* W    = (which == 0) ? Wq : (which == 1) ? Wk : (which == 2) ? Wv : Ws;
    const float* bias = (which == 0) ? bq : (which == 1) ? bk : (which == 2) ? bv : nullptr;

    float wcol[D];
    #pragma unroll
    for (int i = 0; i < D; i++) wcol[i] = W[i * 64 + j];
    float bj = (which == 3) ? 0.0f : bias[j];

    __syncthreads();

    unsigned short* KVus = (unsigned short*)KV;

    for (int n = 0; n < cnt; n += 2) {
        float acc0 = bj, acc1 = bj;
        const float4* r0 = (const float4*)sh[n];
        const float4* r1 = (const float4*)sh[n + 1];
        #pragma unroll
        for (int i4 = 0; i4 < D / 4; i4++) {
            float4 h0 = r0[i4];
            float4 h1 = r1[i4];
            acc0 = fmaf(h0.x, wcol[4 * i4 + 0], acc0);
            acc1 = fmaf(h1.x, wcol[4 * i4 + 0], acc1);
            acc0 = fmaf(h0.y, wcol[4 * i4 + 1], acc0);
            acc1 = fmaf(h1.y, wcol[4 * i4 + 1], acc1);
            acc0 = fmaf(h0.z, wcol[4 * i4 + 2], acc0);
            acc1 = fmaf(h1.z, wcol[4 * i4 + 2], acc1);
            acc0 = fmaf(h0.w, wcol[4 * i4 + 3], acc0);
            acc1 = fmaf(h1.w, wcol[4 * i4 + 3], acc1);
        }
        if (which == 1 || which == 2) {
            // K -> low ushort, V -> high ushort of KV[n*64+j]
            int o0 = ((n0 + n) * 64 + j) * 2 + (which - 1);
            KVus[o0]       = f32_to_bf16_rne(acc0);
            KVus[o0 + 128] = f32_to_bf16_rne(acc1);
        } else {
            float* out = (which == 0) ? Q : S;
            out[(n0 + n) * 64 + j]     = acc0;
            out[(n0 + n + 1) * 64 + j] = acc1;
        }
    }
}

// ---------------------------------------------------------------------------
// Kernel: per-node attention aggregation + skip + LayerNorm (+res/relu).
// One wave per node. No max-subtraction (scores are O(3); exp is fp32-safe,
// alpha = exp(s)/sum exp(s) identical to ref). bf16-packed KV: one dword
// gather per edge per lane. 4-edge unroll, two accumulator pairs.
template <int HEADS, bool RES, bool RELU>
__global__ __launch_bounds__(256) void agg_kernel(
                           const float* __restrict__ Q, const unsigned int* __restrict__ KV,
                           const float* __restrict__ S,
                           const int* __restrict__ row_ptr, const int* __restrict__ colb,
                           const float* __restrict__ g, const float* __restrict__ b,
                           const float* __restrict__ h_in, float* __restrict__ h_out) {
    constexpr int C = HID / HEADS;
    int lane = threadIdx.x & 63;
    int n = blockIdx.x * 4 + (threadIdx.x >> 6);

    const float scale = rsqrtf((float)C);
    float q = Q[n * 64 + lane] * scale;          // fold 1/sqrt(C) into q
    float sval = S[n * 64 + lane];
    float resv = RES ? h_in[n * 64 + lane] : 0.0f;
    int beg = row_ptr[n], end = row_ptr[n + 1];

    float ssumA = 0.0f, accA = 0.0f, ssumB = 0.0f, accB = 0.0f;

    for (int base = beg; base < end; base += 64) {
        int cnt = min(64, end - base);
        int src_l = (base + lane < end) ? colb[base + lane] : 0;
        int j = 0;
        for (; j + 4 <= cnt; j += 4) {
            int s0 = __builtin_amdgcn_readlane(src_l, j);
            int s1 = __builtin_amdgcn_readlane(src_l, j + 1);
            int s2 = __builtin_amdgcn_readlane(src_l, j + 2);
            int s3 = __builtin_amdgcn_readlane(src_l, j + 3);
            unsigned int kv0 = KV[(size_t)s0 * 64 + lane];
            unsigned int kv1 = KV[(size_t)s1 * 64 + lane];
            unsigned int kv2 = KV[(size_t)s2 * 64 + lane];
            unsigned int kv3 = KV[(size_t)s3 * 64 + lane];
            float k0 = __uint_as_float(kv0 << 16), v0 = __uint_as_float(kv0 & 0xffff0000u);
            float k1 = __uint_as_float(kv1 << 16), v1 = __uint_as_float(kv1 & 0xffff0000u);
            float k2 = __uint_as_float(kv2 << 16), v2 = __uint_as_float(kv2 & 0xffff0000u);
            float k3 = __uint_as_float(kv3 << 16), v3 = __uint_as_float(kv3 & 0xffff0000u);
            float t0 = q * k0, t1 = q * k1, t2 = q * k2, t3 = q * k3;
            #pragma unroll
            for (int off = 1; off < C; off <<= 1) {
                t0 += __shfl_xor(t0, off);
                t1 += __shfl_xor(t1, off);
                t2 += __shfl_xor(t2, off);
                t3 += __shfl_xor(t3, off);
            }
            float p0 = __expf(t0), p1 = __expf(t1);
            float p2 = __expf(t2), p3 = __expf(t3);
            ssumA += p0; accA = fmaf(p0, v0, accA);
            ssumB += p1; accB = fmaf(p1, v1, accB);
            ssumA += p2; accA = fmaf(p2, v2, accA);
            ssumB += p3; accB = fmaf(p3, v3, accB);
        }
        for (; j < cnt; j++) {
            int s0 = __builtin_amdgcn_readlane(src_l, j);
            unsigned int kv0 = KV[(size_t)s0 * 64 + lane];
            float k0 = __uint_as_float(kv0 << 16), v0 = __uint_as_float(kv0 & 0xffff0000u);
            float t0 = q * k0;
            #pragma unroll
            for (int off = 1; off < C; off <<= 1) t0 += __shfl_xor(t0, off);
            float p0 = __expf(t0);
            ssumA += p0; accA = fmaf(p0, v0, accA);
        }
    }

    float outf = (accA + accB) / ((ssumA + ssumB) + 1e-16f) + sval;

    float s = outf;
    #pragma unroll
    for (int off = 1; off < 64; off <<= 1) s += __shfl_xor(s, off);
    float mu = s * (1.0f / 64.0f);
    float d = outf - mu;
    float vs = d * d;
    #pragma unroll
    for (int off = 1; off < 64; off <<= 1) vs += __shfl_xor(vs, off);
    float var = vs * (1.0f / 64.0f);
    float y = d * rsqrtf(var + 1e-5f) * g[lane] + b[lane];
    if (RES)  y += 0.1f * resv;
    if (RELU) y = fmaxf(y, 0.0f);
    h_out[n * 64 + lane] = y;
}

// ---------------------------------------------------------------------------
// Kernel: final two MLP heads. One wave per node.
__global__ void head_kernel(const float* __restrict__ h,
                            const float* __restrict__ Wr1, const float* __restrict__ br1,
                            const float* __restrict__ Wr2, const float* __restrict__ br2,
                            const float* __restrict__ Wt1, const float* __restrict__ bt1,
                            const float* __restrict__ Wt2, const float* __restrict__ bt2,
                            float* __restrict__ out) {
    __shared__ float sh[4][HID];
    int wave = threadIdx.x >> 6;
    int lane = threadIdx.x & 63;
    int n = blockIdx.x * 4 + wave;
    sh[wave][lane] = h[n * 64 + lane];
    __syncthreads();
    int half = lane >> 5;
    int j = lane & 31;
    const float* W1 = half ? Wt1 : Wr1;
    const float* b1 = half ? bt1 : br1;
    const float* W2 = half ? Wt2 : Wr2;
    const float* b2 = half ? bt2 : br2;
    float a = b1[j];
    #pragma unroll 8
    for (int i = 0; i < 64; i++) a = fmaf(sh[wave][i], W1[i * 32 + j], a);
    a = fmaxf(a, 0.0f);
    float r = a * W2[j];
    #pragma unroll
    for (int off = 1; off < 32; off <<= 1) r += __shfl_xor(r, off);
    if (j == 0) out[n * 2 + half] = r + b2[0];
}

// ---------------------------------------------------------------------------
extern "C" void kernel_launch(void* const* d_in, const int* in_sizes, int n_in,
                              void* d_out, int out_size, void* d_ws, size_t ws_size,
                              hipStream_t stream) {
    const float* x    = (const float*)d_in[0];
    const int*   ei   = (const int*)d_in[1];
    const int*   src  = ei;
    const int*   dst  = ei + N_EDGES;
    const float* ln0g = (const float*)d_in[2];
    const float* ln0b = (const float*)d_in[3];

    const float* P[27];
    for (int i = 0; i < 27; i++) P[i] = (const float*)d_in[4 + i];
    const float* Wr1 = (const float*)d_in[31];
    const float* br1 = (const float*)d_in[32];
    const float* Wr2 = (const float*)d_in[33];
    const float* br2 = (const float*)d_in[34];
    const float* Wt1 = (const float*)d_in[35];
    const float* bt1 = (const float*)d_in[36];
    const float* Wt2 = (const float*)d_in[37];
    const float* bt2 = (const float*)d_in[38];

    float* out = (float*)d_out;

    // workspace layout
    float* hbuf0 = (float*)d_ws;                 // N*64
    float* hbuf1 = hbuf0 + N_NODES * 64;         // N*64
    float* Qb    = hbuf1 + N_NODES * 64;         // N*64
    float* Sb    = Qb + N_NODES * 64;            // N*64
    unsigned int* KVb = (unsigned int*)(Sb + N_NODES * 64);   // N*64 uint
    int* row_ptr = (int*)(KVb + N_NODES * 64);   // N+1
    int* cursor  = row_ptr + (N_NODES + 1);      // N
    int* deg     = cursor + N_NODES;             // N
    int* colb    = deg + N_NODES;                // E
    int* csum    = colb + N_EDGES;               // N_CHUNKS
    int* coff    = csum + N_CHUNKS;              // N_CHUNKS

    // ---- graph structure (rebuilt every launch; ws is re-poisoned) ----
    hipMemsetAsync(deg, 0, N_NODES * sizeof(int), stream);
    ln0_kernel<<<6250, 256, 0, stream>>>(x, ln0g, ln0b, hbuf0);
    deg_kernel<<<(N_EDGES + 255) / 256, 256, 0, stream>>>(dst, deg);
    chunk_sum_kernel<<<N_CHUNKS, 256, 0, stream>>>(deg, csum);
    scan_sums_kernel<<<1, 64, 0, stream>>>(csum, coff, row_ptr);
    scan_final_kernel<<<N_CHUNKS, 256, 0, stream>>>(deg, coff, row_ptr, cursor);
    fill_kernel<<<(N_EDGES + 255) / 256, 256, 0, stream>>>(src, dst, cursor, colb);

    // ---- layer 0: 32 -> 64, heads=4, no residual, relu ----
    qkvs_kernel<32><<<N_QKVS_BLOCKS, 256, 0, stream>>>(hbuf0,
        P[0], P[1], P[2], P[3], P[4], P[5], P[6], Qb, KVb, Sb);
    agg_kernel<4, false, true><<<12500, 256, 0, stream>>>(Qb, KVb, Sb,
        row_ptr, colb, P[7], P[8], nullptr, hbuf1);

    // ---- layer 1: 64 -> 64, heads=4, residual, relu ----
    qkvs_kernel<64><<<N_QKVS_BLOCKS, 256, 0, stream>>>(hbuf1,
        P[9], P[10], P[11], P[12], P[13], P[14], P[15], Qb, KVb, Sb);
    agg_kernel<4, true, true><<<12500, 256, 0, stream>>>(Qb, KVb, Sb,
        row_ptr, colb, P[16], P[17], hbuf1, hbuf0);

    // ---- layer 2: 64 -> 64, heads=1, residual, no relu ----
    qkvs_kernel<64><<<N_QKVS_BLOCKS, 256, 0, stream>>>(hbuf0,
        P[18], P[19], P[20], P[21], P[22], P[23], P[24], Qb, KVb, Sb);
    agg_kernel<1, true, false><<<12500, 256, 0, stream>>>(Qb, KVb, Sb,
        row_ptr, colb, P[25], P[26], hbuf0, hbuf1);

    // ---- MLP heads ----
    head_kernel<<<12500, 256, 0, stream>>>(hbuf1,
        Wr1, br1, Wr2, br2, Wt1, bt1, Wt2, bt2, out);
}